// Round 1
// 770.134 us; speedup vs baseline: 1.0562x; 1.0562x over previous
//
#include <hip/hip_runtime.h>
#include <cstdint>

typedef unsigned short u16;
using bf16x8  = __attribute__((ext_vector_type(8))) __bf16;
using floatx4 = __attribute__((ext_vector_type(4))) float;

__device__ __forceinline__ u16 f2bf(float f) {
    uint32_t u = __builtin_bit_cast(uint32_t, f);
    u += 0x7fffu + ((u >> 16) & 1u);   // RNE
    return (u16)(u >> 16);
}
__device__ __forceinline__ float bf2f(u16 h) {
    uint32_t u = ((uint32_t)h) << 16;
    return __builtin_bit_cast(float, u);
}

// async global->LDS, 16B per lane (global_load_lds_dwordx4).
// LDS dest is wave-uniform base + lane*16; global src is per-lane.
__device__ __forceinline__ void gload16(const u16* g, u16* l) {
    __builtin_amdgcn_global_load_lds(
        (const __attribute__((address_space(1))) unsigned int*)g,
        (__attribute__((address_space(3))) unsigned int*)l,
        16, 0, 0);
}

// ---------------------------------------------------------------------------
// ROIAlign: feat [2,80,80,20,128] f32 -> A1 [50176, 896] bf16, k = z*128+c
// one block per box; 8 point-slots x 32 threads x float4 channels
// ---------------------------------------------------------------------------
__global__ __launch_bounds__(256) void k_roialign(
    const float* __restrict__ feat, const float* __restrict__ boxes,
    const int* __restrict__ bidx, u16* __restrict__ A1)
{
    const int n = blockIdx.x;
    const int t = threadIdx.x;
    const float s = 5.0f; // VOXEL_SCALE * POOLER_SCALE
    const float x1 = boxes[n*6+0]*s, y1 = boxes[n*6+1]*s, z1 = boxes[n*6+2]*s;
    const float x2 = boxes[n*6+3]*s, y2 = boxes[n*6+4]*s, z2 = boxes[n*6+5]*s;
    const float binx = fmaxf(x2-x1, 1.0f) * (1.0f/7.0f);
    const float biny = fmaxf(y2-y1, 1.0f) * (1.0f/7.0f);
    const float binz = fmaxf(z2-z1, 1.0f) * (1.0f/7.0f);
    const int b = bidx[n];
    const float* fb = feat + (size_t)b * 80 * 80 * 20 * 128;
    const int c4   = (t & 31) * 4;
    const int slot = t >> 5;

    for (int p = slot; p < 343; p += 8) {
        const int xq = p / 49;
        const int rem = p - xq * 49;
        const int yq = rem / 7;
        const int zq = rem - yq * 7;
        const float px = x1 + ((float)xq + 0.5f) * binx;
        const float py = y1 + ((float)yq + 0.5f) * biny;
        const float pz = z1 + ((float)zq + 0.5f) * binz;
        const float fx = floorf(px), fy = floorf(py), fz = floorf(pz);
        const float lx = px - fx, ly = py - fy, lz = pz - fz;
        const int xi0 = min(max((int)fx,     0), 79);
        const int xi1 = min(max((int)fx + 1, 0), 79);
        const int yi0 = min(max((int)fy,     0), 79);
        const int yi1 = min(max((int)fy + 1, 0), 79);
        const int zi0 = min(max((int)fz,     0), 19);
        const int zi1 = min(max((int)fz + 1, 0), 19);
        const float wx0 = 1.f-lx, wy0 = 1.f-ly, wz0 = 1.f-lz;
        const float w00 = wx0*wy0, w01 = wx0*ly, w10 = lx*wy0, w11 = lx*ly;
        float a0=0.f, a1=0.f, a2=0.f, a3=0.f;
#define RC(W, XI, YI, ZI) { \
        const float4 v = *(const float4*)(fb + (size_t)(((XI)*80+(YI))*20+(ZI))*128 + c4); \
        a0 = fmaf((W), v.x, a0); a1 = fmaf((W), v.y, a1); \
        a2 = fmaf((W), v.z, a2); a3 = fmaf((W), v.w, a3); }
        RC(w00*wz0, xi0, yi0, zi0); RC(w00*lz, xi0, yi0, zi1);
        RC(w01*wz0, xi0, yi1, zi0); RC(w01*lz, xi0, yi1, zi1);
        RC(w10*wz0, xi1, yi0, zi0); RC(w10*lz, xi1, yi0, zi1);
        RC(w11*wz0, xi1, yi1, zi0); RC(w11*lz, xi1, yi1, zi1);
#undef RC
        const int m = n * 49 + xq * 7 + yq;
        ushort4 o;
        o.x = f2bf(a0); o.y = f2bf(a1); o.z = f2bf(a2); o.w = f2bf(a3);
        *(ushort4*)(A1 + (size_t)m * 896 + zq * 128 + c4) = o;
    }
}

// ---------------------------------------------------------------------------
// conv_w [896,128,7] f32 -> WcT [896 r][896 k] bf16, k = z*128+c
// ---------------------------------------------------------------------------
__global__ __launch_bounds__(256) void k_prep_wc(
    const float* __restrict__ w, u16* __restrict__ out)
{
    const int i = blockIdx.x * 256 + threadIdx.x;   // < 802816 exactly
    const int r = i / 896, k = i % 896;
    const int z = k >> 7, c = k & 127;
    out[i] = f2bf(w[(r * 128 + c) * 7 + z]);
}

// ---------------------------------------------------------------------------
// transpose+cast: in f32 [Kin][896] -> out bf16 [896][Kin]
// PERM=1: out[r][kp] = in[(kp%896)*49 + kp/896][r]  (fc6 k-permutation)
// ---------------------------------------------------------------------------
template <int PERM>
__global__ __launch_bounds__(256) void k_transpose(
    const float* __restrict__ in, u16* __restrict__ out, int Kin)
{
    __shared__ u16 tile[64][72];
    const int kp0 = blockIdx.x * 64, r0 = blockIdx.y * 64;
    const int t = threadIdx.x;
#pragma unroll
    for (int it = 0; it < 16; ++it) {
        const int idx = it * 256 + t;
        const int i = idx >> 6, rl = idx & 63;
        const int kp = kp0 + i;
        const int k = PERM ? (kp % 896) * 49 + (kp / 896) : kp;
        tile[i][rl] = f2bf(in[(size_t)k * 896 + r0 + rl]);
    }
    __syncthreads();
#pragma unroll
    for (int it = 0; it < 16; ++it) {
        const int idx = it * 256 + t;
        const int rl = idx >> 6, i = idx & 63;
        out[(size_t)(r0 + rl) * Kin + kp0 + i] = tile[i][rl];
    }
}

// ---------------------------------------------------------------------------
// GEMM: C[M,N] = A[M,K] * Bt[N,K]^T, bf16 inputs, fp32 accum.
// 128x128 tile, BK=32, 4 waves (2x2), per-wave 4x4 of 16x16x32 MFMA.
// Staging: global_load_lds width-16, linear LDS [128][32] (m97 structure).
// EPI==0: out bf16 = acc + bias[n]; fused BN sum/sumsq atomics.
//         1-D grid 2744 = 8 XCD chunks x 343, N-tile fastest within a chunk
//         so the 7 blocks sharing an A-panel hit the same XCD's L2.
// EPI==1: fp32 partial store to outF + blockIdx.z * partStride (split-K).
// ---------------------------------------------------------------------------
template <int EPI>
__global__ __launch_bounds__(256) void k_gemm(
    const u16* __restrict__ A, const u16* __restrict__ Bt,
    float* __restrict__ outF, u16* __restrict__ outH,
    const float* __restrict__ bias, float* __restrict__ bnsum, float* __restrict__ bnsq,
    int Astride, int Bstride, int kpc, int ktot, int partStride)
{
    __shared__ __align__(16) u16 lA[128 * 32];   // linear: gload_lds dest
    __shared__ __align__(16) u16 lB[128 * 32];
    const int t = threadIdx.x;
    const int wave = t >> 6, lane = t & 63;
    const int wm = wave & 1, wn = wave >> 1;
    const int quad = lane >> 4, lr = lane & 15;

    int mt, nt, kz;
    if (EPI == 0) {
        const int wg = blockIdx.x;                 // 2744 = 8 * 343, bijective
        const int swz = (wg & 7) * 343 + (wg >> 3);
        nt = swz % 7; mt = swz / 7; kz = 0;        // 343 = 49*7 -> nt cycles fastest
    } else {
        mt = blockIdx.x; nt = blockIdx.y; kz = blockIdx.z;
    }
    const size_t m0 = (size_t)mt * 128;
    const size_t n0 = (size_t)nt * 128;
    const int kbeg = kz * kpc;
    const int kend = min(kbeg + kpc, ktot);

    floatx4 acc[4][4];
    const floatx4 zero = {0.f, 0.f, 0.f, 0.f};
#pragma unroll
    for (int a = 0; a < 4; ++a)
#pragma unroll
        for (int bq = 0; bq < 4; ++bq) acc[a][bq] = zero;

    // staging: chunk c in [0,8) = LDS bytes [c*1024, c*1024+1024)
    //        = tile rows c*16 + (lane>>2), elements (lane&3)*8 .. +7
    const int ch0 = wave * 2, ch1 = ch0 + 1;
    const int sr0 = ch0 * 16 + (lane >> 2);
    const int sr1 = sr0 + 16;
    const int sc  = (lane & 3) * 8;
    const u16* gA0 = A  + (m0 + sr0) * (size_t)Astride + (size_t)kbeg * 32 + sc;
    const u16* gA1 = A  + (m0 + sr1) * (size_t)Astride + (size_t)kbeg * 32 + sc;
    const u16* gB0 = Bt + (n0 + sr0) * (size_t)Bstride + (size_t)kbeg * 32 + sc;
    const u16* gB1 = Bt + (n0 + sr1) * (size_t)Bstride + (size_t)kbeg * 32 + sc;
    u16* lA0 = lA + ch0 * 512;   // wave-uniform LDS bases (512 u16 = 1024 B)
    u16* lA1 = lA + ch1 * 512;
    u16* lB0 = lB + ch0 * 512;
    u16* lB1 = lB + ch1 * 512;

    for (int ks = kbeg; ks < kend; ++ks) {
        __syncthreads();                       // all waves done reading prev tile
        gload16(gA0, lA0); gload16(gA1, lA1);
        gload16(gB0, lB0); gload16(gB1, lB1);
        gA0 += 32; gA1 += 32; gB0 += 32; gB1 += 32;
        __syncthreads();                       // compiler drains vmcnt(0) here
        bf16x8 af[4], bfr[4];
#pragma unroll
        for (int mt4 = 0; mt4 < 4; ++mt4)
            af[mt4] = *(const bf16x8*)(lA + (wm * 64 + mt4 * 16 + lr) * 32 + quad * 8);
#pragma unroll
        for (int nt4 = 0; nt4 < 4; ++nt4)
            bfr[nt4] = *(const bf16x8*)(lB + (wn * 64 + nt4 * 16 + lr) * 32 + quad * 8);
#pragma unroll
        for (int mt4 = 0; mt4 < 4; ++mt4)
#pragma unroll
            for (int nt4 = 0; nt4 < 4; ++nt4)
                acc[mt4][nt4] = __builtin_amdgcn_mfma_f32_16x16x32_bf16(
                    af[mt4], bfr[nt4], acc[mt4][nt4], 0, 0, 0);
    }

    if (EPI == 0) {
#pragma unroll
        for (int nt4 = 0; nt4 < 4; ++nt4) {
            const int n = (int)n0 + wn * 64 + nt4 * 16 + lr;
            const float bv = bias[n];
            float s1 = 0.f, s2 = 0.f;
#pragma unroll
            for (int mt4 = 0; mt4 < 4; ++mt4) {
#pragma unroll
                for (int j = 0; j < 4; ++j) {
                    const int m = (int)m0 + wm * 64 + mt4 * 16 + quad * 4 + j;
                    const float v = acc[mt4][nt4][j] + bv;
                    outH[(size_t)m * 896 + n] = f2bf(v);
                    s1 += v;
                    s2 = fmaf(v, v, s2);
                }
            }
            s1 += __shfl_xor(s1, 16); s1 += __shfl_xor(s1, 32);
            s2 += __shfl_xor(s2, 16); s2 += __shfl_xor(s2, 32);
            if (quad == 0) {
                atomicAdd(&bnsum[n], s1);
                atomicAdd(&bnsq[n],  s2);
            }
        }
    } else {
        float* po = outF + (size_t)blockIdx.z * partStride;
#pragma unroll
        for (int nt4 = 0; nt4 < 4; ++nt4) {
            const int n = (int)n0 + wn * 64 + nt4 * 16 + lr;
#pragma unroll
            for (int mt4 = 0; mt4 < 4; ++mt4) {
#pragma unroll
                for (int j = 0; j < 4; ++j) {
                    const int m = (int)m0 + wm * 64 + mt4 * 16 + quad * 4 + j;
                    po[(size_t)m * 896 + n] = acc[mt4][nt4][j];
                }
            }
        }
    }
}

// ---------------------------------------------------------------------------
// BN apply + ReLU, in place on y bf16 [50176, 896] (becomes x2)
// ---------------------------------------------------------------------------
__global__ __launch_bounds__(256) void k_bn_apply(
    u16* __restrict__ y, const float* __restrict__ s1, const float* __restrict__ s2,
    const float* __restrict__ gamma, const float* __restrict__ beta)
{
    const size_t i = ((size_t)blockIdx.x * 256 + threadIdx.x) * 8;
    uint4 d = *(const uint4*)(y + i);
    const u16* h = (const u16*)&d;
    const int r0 = (int)(i % 896);
    __align__(16) u16 o[8];
    const float invM = 1.0f / 50176.0f;
#pragma unroll
    for (int j = 0; j < 8; ++j) {
        const int r = r0 + j;
        const float mu  = s1[r] * invM;
        const float var = fmaf(-mu, mu, s2[r] * invM);
        const float rs  = rsqrtf(var + 1e-5f);
        const float v   = (bf2f(h[j]) - mu) * rs * gamma[r] + beta[r];
        o[j] = f2bf(fmaxf(v, 0.f));
    }
    *(uint4*)(y + i) = *(const uint4*)o;
}

// ---------------------------------------------------------------------------
// split-K reduce + bias + relu -> bf16 (fc6 out / GEMM3 input)
// ---------------------------------------------------------------------------
__global__ __launch_bounds__(256) void k_x3(
    const float* __restrict__ part, const float* __restrict__ bias, u16* __restrict__ x3)
{
    const size_t i = ((size_t)blockIdx.x * 256 + threadIdx.x) * 4;
    float a0=0.f, a1=0.f, a2=0.f, a3=0.f;
#pragma unroll
    for (int c = 0; c < 16; ++c) {
        const float4 v = *(const float4*)(part + (size_t)c * 917504 + i);
        a0 += v.x; a1 += v.y; a2 += v.z; a3 += v.w;
    }
    const int r = (int)(i % 896);
    ushort4 o;
    o.x = f2bf(fmaxf(a0 + bias[r+0], 0.f));
    o.y = f2bf(fmaxf(a1 + bias[r+1], 0.f));
    o.z = f2bf(fmaxf(a2 + bias[r+2], 0.f));
    o.w = f2bf(fmaxf(a3 + bias[r+3], 0.f));
    *(ushort4*)(x3 + i) = o;
}

// split-K reduce + bias + relu -> fp32 final output
__global__ __launch_bounds__(256) void k_out(
    const float* __restrict__ part, const float* __restrict__ bias, float* __restrict__ out)
{
    const size_t i = ((size_t)blockIdx.x * 256 + threadIdx.x) * 4;
    float a0=0.f, a1=0.f, a2=0.f, a3=0.f;
#pragma unroll
    for (int c = 0; c < 4; ++c) {
        const float4 v = *(const float4*)(part + (size_t)c * 917504 + i);
        a0 += v.x; a1 += v.y; a2 += v.z; a3 += v.w;
    }
    const int r = (int)(i % 896);
    float4 o;
    o.x = fmaxf(a0 + bias[r+0], 0.f);
    o.y = fmaxf(a1 + bias[r+1], 0.f);
    o.z = fmaxf(a2 + bias[r+2], 0.f);
    o.w = fmaxf(a3 + bias[r+3], 0.f);
    *(float4*)(out + i) = o;
}

// ---------------------------------------------------------------------------
extern "C" void kernel_launch(void* const* d_in, const int* in_sizes, int n_in,
                              void* d_out, int out_size, void* d_ws, size_t ws_size,
                              hipStream_t stream)
{
    (void)in_sizes; (void)n_in; (void)out_size; (void)ws_size;
    const float* features = (const float*)d_in[0];
    const float* boxes    = (const float*)d_in[1];
    const float* conv_w   = (const float*)d_in[2];
    const float* conv_b   = (const float*)d_in[3];
    const float* gamma    = (const float*)d_in[4];
    const float* beta     = (const float*)d_in[5];
    const float* fc6_w    = (const float*)d_in[6];
    const float* fc6_b    = (const float*)d_in[7];
    const float* fc7_w    = (const float*)d_in[8];
    const float* fc7_b    = (const float*)d_in[9];
    const int*   batch_idx = (const int*)d_in[10];
    float* out = (float*)d_out;
    char* ws = (char*)d_ws;

    size_t off = 0;
    auto alloc = [&](size_t b) { size_t o = off; off += (b + 255) & ~(size_t)255; return o; };
    const size_t oA1   = alloc(50176ull * 896 * 2);   // 89,915,392
    const size_t oWcT  = alloc(896ull * 896 * 2);
    const size_t oY    = alloc(50176ull * 896 * 2);
    const size_t oF6T  = alloc(43904ull * 896 * 2);   // 78,675,968
    const size_t oF7T  = alloc(896ull * 896 * 2);
    const size_t oStat = alloc(8192);
    // A1 region is dead after GEMM1 -> reuse for split-K partials + x3
    const size_t oP2 = oA1;                       // 16 * 917504 * 4 = 58,720,256
    const size_t oX3 = oA1 + 58720256;            //  1,835,008
    const size_t oP3 = oX3 + 1835008;             // 14,680,064 (total 75.2 MB < 89.9 MB)

    u16*   A1    = (u16*)(ws + oA1);
    u16*   WcT   = (u16*)(ws + oWcT);
    u16*   Y     = (u16*)(ws + oY);
    u16*   F6T   = (u16*)(ws + oF6T);
    u16*   F7T   = (u16*)(ws + oF7T);
    float* bnsum = (float*)(ws + oStat);
    float* bnsq  = bnsum + 1024;
    float* P2    = (float*)(ws + oP2);
    u16*   X3    = (u16*)(ws + oX3);
    float* P3    = (float*)(ws + oP3);

    // weight prep
    k_prep_wc<<<3136, 256, 0, stream>>>(conv_w, WcT);
    k_transpose<1><<<dim3(686, 14), 256, 0, stream>>>(fc6_w, F6T, 43904);
    k_transpose<0><<<dim3(14, 14), 256, 0, stream>>>(fc7_w, F7T, 896);
    hipMemsetAsync(ws + oStat, 0, 8192, stream);

    // ROIAlign -> A1 [50176, 896] bf16
    k_roialign<<<1024, 256, 0, stream>>>(features, boxes, batch_idx, A1);

    // GEMM1: y = A1 @ WcT^T + conv_b, fused BN stats. M=50176 N=896 K=896
    // 1-D XCD-swizzled grid: 2744 = 8 * 343
    k_gemm<0><<<dim3(2744, 1, 1), 256, 0, stream>>>(
        A1, WcT, nullptr, Y, conv_b, bnsum, bnsq, 896, 896, 28, 28, 0);

    // BN + ReLU in place (Y becomes x2 viewed as [1024, 43904], k'=xy*896+r)
    k_bn_apply<<<21952, 256, 0, stream>>>(Y, bnsum, bnsq, gamma, beta);

    // GEMM2 (fc6): M=1024 N=896 K=43904, split-K 16 -> P2
    k_gemm<1><<<dim3(8, 7, 16), 256, 0, stream>>>(
        Y, F6T, P2, nullptr, nullptr, nullptr, nullptr, 43904, 43904, 86, 1372, 917504);
    k_x3<<<896, 256, 0, stream>>>(P2, fc6_b, X3);

    // GEMM3 (fc7): M=1024 N=896 K=896, split-K 4 -> P3
    k_gemm<1><<<dim3(8, 7, 4), 256, 0, stream>>>(
        X3, F7T, P3, nullptr, nullptr, nullptr, nullptr, 896, 896, 7, 28, 917504);
    k_out<<<896, 256, 0, stream>>>(P3, fc7_b, out);
}

// Round 2
// 760.489 us; speedup vs baseline: 1.0695x; 1.0127x over previous
//
#include <hip/hip_runtime.h>
#include <cstdint>

typedef unsigned short u16;
using bf16x8  = __attribute__((ext_vector_type(8))) __bf16;
using floatx4 = __attribute__((ext_vector_type(4))) float;

__device__ __forceinline__ u16 f2bf(float f) {
    uint32_t u = __builtin_bit_cast(uint32_t, f);
    u += 0x7fffu + ((u >> 16) & 1u);   // RNE
    return (u16)(u >> 16);
}
__device__ __forceinline__ float bf2f(u16 h) {
    uint32_t u = ((uint32_t)h) << 16;
    return __builtin_bit_cast(float, u);
}

// async global->LDS, 16B per lane (global_load_lds_dwordx4).
// LDS dest is wave-uniform base + lane*16; global src is per-lane.
__device__ __forceinline__ void gload16(const u16* g, u16* l) {
    __builtin_amdgcn_global_load_lds(
        (const __attribute__((address_space(1))) unsigned int*)g,
        (__attribute__((address_space(3))) unsigned int*)l,
        16, 0, 0);
}

// ---------------------------------------------------------------------------
// ROIAlign: feat [2,80,80,20,128] f32 -> A1 [50176, 896] bf16, k = z*128+c
// one block per box; 8 point-slots x 32 threads x float4 channels
// ---------------------------------------------------------------------------
__global__ __launch_bounds__(256) void k_roialign(
    const float* __restrict__ feat, const float* __restrict__ boxes,
    const int* __restrict__ bidx, u16* __restrict__ A1)
{
    const int n = blockIdx.x;
    const int t = threadIdx.x;
    const float s = 5.0f; // VOXEL_SCALE * POOLER_SCALE
    const float x1 = boxes[n*6+0]*s, y1 = boxes[n*6+1]*s, z1 = boxes[n*6+2]*s;
    const float x2 = boxes[n*6+3]*s, y2 = boxes[n*6+4]*s, z2 = boxes[n*6+5]*s;
    const float binx = fmaxf(x2-x1, 1.0f) * (1.0f/7.0f);
    const float biny = fmaxf(y2-y1, 1.0f) * (1.0f/7.0f);
    const float binz = fmaxf(z2-z1, 1.0f) * (1.0f/7.0f);
    const int b = bidx[n];
    const float* fb = feat + (size_t)b * 80 * 80 * 20 * 128;
    const int c4   = (t & 31) * 4;
    const int slot = t >> 5;

    for (int p = slot; p < 343; p += 8) {
        const int xq = p / 49;
        const int rem = p - xq * 49;
        const int yq = rem / 7;
        const int zq = rem - yq * 7;
        const float px = x1 + ((float)xq + 0.5f) * binx;
        const float py = y1 + ((float)yq + 0.5f) * biny;
        const float pz = z1 + ((float)zq + 0.5f) * binz;
        const float fx = floorf(px), fy = floorf(py), fz = floorf(pz);
        const float lx = px - fx, ly = py - fy, lz = pz - fz;
        const int xi0 = min(max((int)fx,     0), 79);
        const int xi1 = min(max((int)fx + 1, 0), 79);
        const int yi0 = min(max((int)fy,     0), 79);
        const int yi1 = min(max((int)fy + 1, 0), 79);
        const int zi0 = min(max((int)fz,     0), 19);
        const int zi1 = min(max((int)fz + 1, 0), 19);
        const float wx0 = 1.f-lx, wy0 = 1.f-ly, wz0 = 1.f-lz;
        const float w00 = wx0*wy0, w01 = wx0*ly, w10 = lx*wy0, w11 = lx*ly;
        float a0=0.f, a1=0.f, a2=0.f, a3=0.f;
#define RC(W, XI, YI, ZI) { \
        const float4 v = *(const float4*)(fb + (size_t)(((XI)*80+(YI))*20+(ZI))*128 + c4); \
        a0 = fmaf((W), v.x, a0); a1 = fmaf((W), v.y, a1); \
        a2 = fmaf((W), v.z, a2); a3 = fmaf((W), v.w, a3); }
        RC(w00*wz0, xi0, yi0, zi0); RC(w00*lz, xi0, yi0, zi1);
        RC(w01*wz0, xi0, yi1, zi0); RC(w01*lz, xi0, yi1, zi1);
        RC(w10*wz0, xi1, yi0, zi0); RC(w10*lz, xi1, yi0, zi1);
        RC(w11*wz0, xi1, yi1, zi0); RC(w11*lz, xi1, yi1, zi1);
#undef RC
        const int m = n * 49 + xq * 7 + yq;
        ushort4 o;
        o.x = f2bf(a0); o.y = f2bf(a1); o.z = f2bf(a2); o.w = f2bf(a3);
        *(ushort4*)(A1 + (size_t)m * 896 + zq * 128 + c4) = o;
    }
}

// ---------------------------------------------------------------------------
// conv_w [896,128,7] f32 -> WcT [896 r][896 k] bf16, k = z*128+c
// ---------------------------------------------------------------------------
__global__ __launch_bounds__(256) void k_prep_wc(
    const float* __restrict__ w, u16* __restrict__ out)
{
    const int i = blockIdx.x * 256 + threadIdx.x;   // < 802816 exactly
    const int r = i / 896, k = i % 896;
    const int z = k >> 7, c = k & 127;
    out[i] = f2bf(w[(r * 128 + c) * 7 + z]);
}

// ---------------------------------------------------------------------------
// transpose+cast: in f32 [Kin][896] -> out bf16 [896][Kin]
// PERM=1: out[r][kp] = in[(kp%896)*49 + kp/896][r]  (fc6 k-permutation)
// ---------------------------------------------------------------------------
template <int PERM>
__global__ __launch_bounds__(256) void k_transpose(
    const float* __restrict__ in, u16* __restrict__ out, int Kin)
{
    __shared__ u16 tile[64][72];
    const int kp0 = blockIdx.x * 64, r0 = blockIdx.y * 64;
    const int t = threadIdx.x;
#pragma unroll
    for (int it = 0; it < 16; ++it) {
        const int idx = it * 256 + t;
        const int i = idx >> 6, rl = idx & 63;
        const int kp = kp0 + i;
        const int k = PERM ? (kp % 896) * 49 + (kp / 896) : kp;
        tile[i][rl] = f2bf(in[(size_t)k * 896 + r0 + rl]);
    }
    __syncthreads();
#pragma unroll
    for (int it = 0; it < 16; ++it) {
        const int idx = it * 256 + t;
        const int rl = idx >> 6, i = idx & 63;
        out[(size_t)(r0 + rl) * Kin + kp0 + i] = tile[i][rl];
    }
}

// ---------------------------------------------------------------------------
// GEMM: C[M,N] = A[M,K] * Bt[N,K]^T, bf16 inputs, fp32 accum.
// 128x128 tile, BK=32, 4 waves (2x2), per-wave 4x4 of 16x16x32 MFMA.
// Staging: global_load_lds width-16, DOUBLE-BUFFERED depth-1 prefetch
// (T3 minimum 2-phase recipe): issue next tile's loads before computing
// current; raw s_barrier + explicit vmcnt(0) AFTER compute so HBM/L3
// latency hides under ds_read+MFMA instead of serializing.
// EPI==0: out bf16 = acc + bias[n]; fused BN sum/sumsq atomics.
//         1-D grid 2744 = 8 XCD chunks x 343, N-tile fastest within a chunk.
// EPI==1: fp32 partial store to outF + blockIdx.z * partStride (split-K).
// ---------------------------------------------------------------------------
template <int EPI>
__global__ __launch_bounds__(256) void k_gemm(
    const u16* __restrict__ A, const u16* __restrict__ Bt,
    float* __restrict__ outF, u16* __restrict__ outH,
    const float* __restrict__ bias, float* __restrict__ bnsum, float* __restrict__ bnsq,
    int Astride, int Bstride, int kpc, int ktot, int partStride)
{
    __shared__ __align__(16) u16 lA[2 * 128 * 32];   // 2 buffers x 8 KB
    __shared__ __align__(16) u16 lB[2 * 128 * 32];
    const int t = threadIdx.x;
    const int wave = t >> 6, lane = t & 63;
    const int wm = wave & 1, wn = wave >> 1;
    const int quad = lane >> 4, lr = lane & 15;

    int mt, nt, kz;
    if (EPI == 0) {
        const int wg = blockIdx.x;                 // 2744 = 8 * 343, bijective
        const int swz = (wg & 7) * 343 + (wg >> 3);
        nt = swz % 7; mt = swz / 7; kz = 0;        // nt cycles fastest
    } else {
        mt = blockIdx.x; nt = blockIdx.y; kz = blockIdx.z;
    }
    const size_t m0 = (size_t)mt * 128;
    const size_t n0 = (size_t)nt * 128;
    const int kbeg = kz * kpc;
    const int kend = min(kbeg + kpc, ktot);

    floatx4 acc[4][4];
    const floatx4 zero = {0.f, 0.f, 0.f, 0.f};
#pragma unroll
    for (int a = 0; a < 4; ++a)
#pragma unroll
        for (int bq = 0; bq < 4; ++bq) acc[a][bq] = zero;

    // staging: chunk c in [0,8) = LDS bytes [c*1024, c*1024+1024)
    //        = tile rows c*16 + (lane>>2), elements (lane&3)*8 .. +7
    const int ch0 = wave * 2, ch1 = ch0 + 1;
    const int sr0 = ch0 * 16 + (lane >> 2);
    const int sr1 = sr0 + 16;
    const int sc  = (lane & 3) * 8;
    const u16* gA0 = A  + (m0 + sr0) * (size_t)Astride + (size_t)kbeg * 32 + sc;
    const u16* gA1 = A  + (m0 + sr1) * (size_t)Astride + (size_t)kbeg * 32 + sc;
    const u16* gB0 = Bt + (n0 + sr0) * (size_t)Bstride + (size_t)kbeg * 32 + sc;
    const u16* gB1 = Bt + (n0 + sr1) * (size_t)Bstride + (size_t)kbeg * 32 + sc;
    const int lo0 = ch0 * 512, lo1 = ch1 * 512;  // u16 offsets, wave-uniform

#define STAGE(buf) { \
    u16* la_ = lA + (buf) * 4096; u16* lb_ = lB + (buf) * 4096; \
    gload16(gA0, la_ + lo0); gload16(gA1, la_ + lo1); \
    gload16(gB0, lb_ + lo0); gload16(gB1, lb_ + lo1); \
    gA0 += 32; gA1 += 32; gB0 += 32; gB1 += 32; }

    // prologue: tile kbeg into buf 0
    STAGE(0);
    asm volatile("s_waitcnt vmcnt(0)" ::: "memory");
    __builtin_amdgcn_s_barrier();

    int cur = 0;
    for (int ks = kbeg; ks < kend; ++ks) {
        if (ks + 1 < kend) STAGE(cur ^ 1);     // next-tile loads fly under compute
        asm volatile("" ::: "memory");          // keep loads issued before ds_reads
        const u16* la = lA + cur * 4096;
        const u16* lb = lB + cur * 4096;
        bf16x8 af[4], bfr[4];
#pragma unroll
        for (int mt4 = 0; mt4 < 4; ++mt4)
            af[mt4] = *(const bf16x8*)(la + (wm * 64 + mt4 * 16 + lr) * 32 + quad * 8);
#pragma unroll
        for (int nt4 = 0; nt4 < 4; ++nt4)
            bfr[nt4] = *(const bf16x8*)(lb + (wn * 64 + nt4 * 16 + lr) * 32 + quad * 8);
#pragma unroll
        for (int mt4 = 0; mt4 < 4; ++mt4)
#pragma unroll
            for (int nt4 = 0; nt4 < 4; ++nt4)
                acc[mt4][nt4] = __builtin_amdgcn_mfma_f32_16x16x32_bf16(
                    af[mt4], bfr[nt4], acc[mt4][nt4], 0, 0, 0);
        asm volatile("s_waitcnt vmcnt(0)" ::: "memory");  // next tile landed
        __builtin_amdgcn_s_barrier();           // all waves done reading cur
        cur ^= 1;
    }
#undef STAGE

    if (EPI == 0) {
#pragma unroll
        for (int nt4 = 0; nt4 < 4; ++nt4) {
            const int n = (int)n0 + wn * 64 + nt4 * 16 + lr;
            const float bv = bias[n];
            float s1 = 0.f, s2 = 0.f;
#pragma unroll
            for (int mt4 = 0; mt4 < 4; ++mt4) {
#pragma unroll
                for (int j = 0; j < 4; ++j) {
                    const int m = (int)m0 + wm * 64 + mt4 * 16 + quad * 4 + j;
                    const float v = acc[mt4][nt4][j] + bv;
                    outH[(size_t)m * 896 + n] = f2bf(v);
                    s1 += v;
                    s2 = fmaf(v, v, s2);
                }
            }
            s1 += __shfl_xor(s1, 16); s1 += __shfl_xor(s1, 32);
            s2 += __shfl_xor(s2, 16); s2 += __shfl_xor(s2, 32);
            if (quad == 0) {
                atomicAdd(&bnsum[n], s1);
                atomicAdd(&bnsq[n],  s2);
            }
        }
    } else {
        float* po = outF + (size_t)blockIdx.z * partStride;
#pragma unroll
        for (int nt4 = 0; nt4 < 4; ++nt4) {
            const int n = (int)n0 + wn * 64 + nt4 * 16 + lr;
#pragma unroll
            for (int mt4 = 0; mt4 < 4; ++mt4) {
#pragma unroll
                for (int j = 0; j < 4; ++j) {
                    const int m = (int)m0 + wm * 64 + mt4 * 16 + quad * 4 + j;
                    po[(size_t)m * 896 + n] = acc[mt4][nt4][j];
                }
            }
        }
    }
}

// ---------------------------------------------------------------------------
// BN apply + ReLU, in place on y bf16 [50176, 896] (becomes x2)
// ---------------------------------------------------------------------------
__global__ __launch_bounds__(256) void k_bn_apply(
    u16* __restrict__ y, const float* __restrict__ s1, const float* __restrict__ s2,
    const float* __restrict__ gamma, const float* __restrict__ beta)
{
    const size_t i = ((size_t)blockIdx.x * 256 + threadIdx.x) * 8;
    uint4 d = *(const uint4*)(y + i);
    const u16* h = (const u16*)&d;
    const int r0 = (int)(i % 896);
    __align__(16) u16 o[8];
    const float invM = 1.0f / 50176.0f;
#pragma unroll
    for (int j = 0; j < 8; ++j) {
        const int r = r0 + j;
        const float mu  = s1[r] * invM;
        const float var = fmaf(-mu, mu, s2[r] * invM);
        const float rs  = rsqrtf(var + 1e-5f);
        const float v   = (bf2f(h[j]) - mu) * rs * gamma[r] + beta[r];
        o[j] = f2bf(fmaxf(v, 0.f));
    }
    *(uint4*)(y + i) = *(const uint4*)o;
}

// ---------------------------------------------------------------------------
// split-K reduce + bias + relu -> bf16 (fc6 out / GEMM3 input), 24 chunks
// ---------------------------------------------------------------------------
__global__ __launch_bounds__(256) void k_x3(
    const float* __restrict__ part, const float* __restrict__ bias, u16* __restrict__ x3)
{
    const size_t i = ((size_t)blockIdx.x * 256 + threadIdx.x) * 4;
    float a0=0.f, a1=0.f, a2=0.f, a3=0.f;
#pragma unroll
    for (int c = 0; c < 24; ++c) {
        const float4 v = *(const float4*)(part + (size_t)c * 917504 + i);
        a0 += v.x; a1 += v.y; a2 += v.z; a3 += v.w;
    }
    const int r = (int)(i % 896);
    ushort4 o;
    o.x = f2bf(fmaxf(a0 + bias[r+0], 0.f));
    o.y = f2bf(fmaxf(a1 + bias[r+1], 0.f));
    o.z = f2bf(fmaxf(a2 + bias[r+2], 0.f));
    o.w = f2bf(fmaxf(a3 + bias[r+3], 0.f));
    *(ushort4*)(x3 + i) = o;
}

// split-K reduce + bias + relu -> fp32 final output, 7 chunks
__global__ __launch_bounds__(256) void k_out(
    const float* __restrict__ part, const float* __restrict__ bias, float* __restrict__ out)
{
    const size_t i = ((size_t)blockIdx.x * 256 + threadIdx.x) * 4;
    float a0=0.f, a1=0.f, a2=0.f, a3=0.f;
#pragma unroll
    for (int c = 0; c < 7; ++c) {
        const float4 v = *(const float4*)(part + (size_t)c * 917504 + i);
        a0 += v.x; a1 += v.y; a2 += v.z; a3 += v.w;
    }
    const int r = (int)(i % 896);
    float4 o;
    o.x = fmaxf(a0 + bias[r+0], 0.f);
    o.y = fmaxf(a1 + bias[r+1], 0.f);
    o.z = fmaxf(a2 + bias[r+2], 0.f);
    o.w = fmaxf(a3 + bias[r+3], 0.f);
    *(float4*)(out + i) = o;
}

// ---------------------------------------------------------------------------
extern "C" void kernel_launch(void* const* d_in, const int* in_sizes, int n_in,
                              void* d_out, int out_size, void* d_ws, size_t ws_size,
                              hipStream_t stream)
{
    (void)in_sizes; (void)n_in; (void)out_size; (void)ws_size;
    const float* features = (const float*)d_in[0];
    const float* boxes    = (const float*)d_in[1];
    const float* conv_w   = (const float*)d_in[2];
    const float* conv_b   = (const float*)d_in[3];
    const float* gamma    = (const float*)d_in[4];
    const float* beta     = (const float*)d_in[5];
    const float* fc6_w    = (const float*)d_in[6];
    const float* fc6_b    = (const float*)d_in[7];
    const float* fc7_w    = (const float*)d_in[8];
    const float* fc7_b    = (const float*)d_in[9];
    const int*   batch_idx = (const int*)d_in[10];
    float* out = (float*)d_out;
    char* ws = (char*)d_ws;

    size_t off = 0;
    auto alloc = [&](size_t b) { size_t o = off; off += (b + 255) & ~(size_t)255; return o; };
    const size_t oA1   = alloc(50176ull * 896 * 2);   // 89,915,392
    const size_t oWcT  = alloc(896ull * 896 * 2);
    const size_t oY    = alloc(50176ull * 896 * 2);
    const size_t oF6T  = alloc(43904ull * 896 * 2);   // 78,675,968
    const size_t oF7T  = alloc(896ull * 896 * 2);
    const size_t oStat = alloc(8192);
    // A1 region is dead after GEMM1 -> reuse:
    //   P2: 24 * 917504 * 4 = 88,080,384  (split-K 24 partials, fc6)
    //   X3: at oA1 + 88,080,384 (1,835,008 B -> exactly fills 89,915,392)
    //   P3: overlaps dead P2 (GEMM3 runs after k_x3): 7 * 3,670,016 = 25.7 MB
    const size_t oP2 = oA1;
    const size_t oX3 = oA1 + 88080384;
    const size_t oP3 = oA1;

    u16*   A1    = (u16*)(ws + oA1);
    u16*   WcT   = (u16*)(ws + oWcT);
    u16*   Y     = (u16*)(ws + oY);
    u16*   F6T   = (u16*)(ws + oF6T);
    u16*   F7T   = (u16*)(ws + oF7T);
    float* bnsum = (float*)(ws + oStat);
    float* bnsq  = bnsum + 1024;
    float* P2    = (float*)(ws + oP2);
    u16*   X3    = (u16*)(ws + oX3);
    float* P3    = (float*)(ws + oP3);

    // weight prep
    k_prep_wc<<<3136, 256, 0, stream>>>(conv_w, WcT);
    k_transpose<1><<<dim3(686, 14), 256, 0, stream>>>(fc6_w, F6T, 43904);
    k_transpose<0><<<dim3(14, 14), 256, 0, stream>>>(fc7_w, F7T, 896);
    hipMemsetAsync(ws + oStat, 0, 8192, stream);

    // ROIAlign -> A1 [50176, 896] bf16
    k_roialign<<<1024, 256, 0, stream>>>(features, boxes, batch_idx, A1);

    // GEMM1: y = A1 @ WcT^T + conv_b, fused BN stats. M=50176 N=896 K=896
    k_gemm<0><<<dim3(2744, 1, 1), 256, 0, stream>>>(
        A1, WcT, nullptr, Y, conv_b, bnsum, bnsq, 896, 896, 28, 28, 0);

    // BN + ReLU in place (Y becomes x2 viewed as [1024, 43904], k'=xy*896+r)
    k_bn_apply<<<21952, 256, 0, stream>>>(Y, bnsum, bnsq, gamma, beta);

    // GEMM2 (fc6): M=1024 N=896 K=43904, split-K 24 -> P2 (kpc=58, last=38)
    k_gemm<1><<<dim3(8, 7, 24), 256, 0, stream>>>(
        Y, F6T, P2, nullptr, nullptr, nullptr, nullptr, 43904, 43904, 58, 1372, 917504);
    k_x3<<<896, 256, 0, stream>>>(P2, fc6_b, X3);

    // GEMM3 (fc7): M=1024 N=896 K=896, split-K 7 -> P3 (kpc=4, 7*4=28 exact)
    k_gemm<1><<<dim3(8, 7, 7), 256, 0, stream>>>(
        X3, F7T, P3, nullptr, nullptr, nullptr, nullptr, 896, 896, 4, 28, 917504);
    k_out<<<896, 256, 0, stream>>>(P3, fc7_b, out);
}

// Round 3
// 751.470 us; speedup vs baseline: 1.0824x; 1.0120x over previous
//
#include <hip/hip_runtime.h>
#include <cstdint>

typedef unsigned short u16;
using bf16x8  = __attribute__((ext_vector_type(8))) __bf16;
using floatx4 = __attribute__((ext_vector_type(4))) float;

__device__ __forceinline__ u16 f2bf(float f) {
    uint32_t u = __builtin_bit_cast(uint32_t, f);
    u += 0x7fffu + ((u >> 16) & 1u);   // RNE
    return (u16)(u >> 16);
}
__device__ __forceinline__ float bf2f(u16 h) {
    uint32_t u = ((uint32_t)h) << 16;
    return __builtin_bit_cast(float, u);
}

// async global->LDS, 16B per lane (global_load_lds_dwordx4).
// LDS dest is wave-uniform base + lane*16; global src is per-lane.
__device__ __forceinline__ void gload16(const u16* g, u16* l) {
    __builtin_amdgcn_global_load_lds(
        (const __attribute__((address_space(1))) unsigned int*)g,
        (__attribute__((address_space(3))) unsigned int*)l,
        16, 0, 0);
}

// ---------------------------------------------------------------------------
// ROIAlign: feat [2,80,80,20,128] f32 -> A1 [50176, 896] bf16, k = z*128+c
// ---------------------------------------------------------------------------
__global__ __launch_bounds__(256) void k_roialign(
    const float* __restrict__ feat, const float* __restrict__ boxes,
    const int* __restrict__ bidx, u16* __restrict__ A1)
{
    const int n = blockIdx.x;
    const int t = threadIdx.x;
    const float s = 5.0f; // VOXEL_SCALE * POOLER_SCALE
    const float x1 = boxes[n*6+0]*s, y1 = boxes[n*6+1]*s, z1 = boxes[n*6+2]*s;
    const float x2 = boxes[n*6+3]*s, y2 = boxes[n*6+4]*s, z2 = boxes[n*6+5]*s;
    const float binx = fmaxf(x2-x1, 1.0f) * (1.0f/7.0f);
    const float biny = fmaxf(y2-y1, 1.0f) * (1.0f/7.0f);
    const float binz = fmaxf(z2-z1, 1.0f) * (1.0f/7.0f);
    const int b = bidx[n];
    const float* fb = feat + (size_t)b * 80 * 80 * 20 * 128;
    const int c4   = (t & 31) * 4;
    const int slot = t >> 5;

    for (int p = slot; p < 343; p += 8) {
        const int xq = p / 49;
        const int rem = p - xq * 49;
        const int yq = rem / 7;
        const int zq = rem - yq * 7;
        const float px = x1 + ((float)xq + 0.5f) * binx;
        const float py = y1 + ((float)yq + 0.5f) * biny;
        const float pz = z1 + ((float)zq + 0.5f) * binz;
        const float fx = floorf(px), fy = floorf(py), fz = floorf(pz);
        const float lx = px - fx, ly = py - fy, lz = pz - fz;
        const int xi0 = min(max((int)fx,     0), 79);
        const int xi1 = min(max((int)fx + 1, 0), 79);
        const int yi0 = min(max((int)fy,     0), 79);
        const int yi1 = min(max((int)fy + 1, 0), 79);
        const int zi0 = min(max((int)fz,     0), 19);
        const int zi1 = min(max((int)fz + 1, 0), 19);
        const float wx0 = 1.f-lx, wy0 = 1.f-ly, wz0 = 1.f-lz;
        const float w00 = wx0*wy0, w01 = wx0*ly, w10 = lx*wy0, w11 = lx*ly;
        float a0=0.f, a1=0.f, a2=0.f, a3=0.f;
#define RC(W, XI, YI, ZI) { \
        const float4 v = *(const float4*)(fb + (size_t)(((XI)*80+(YI))*20+(ZI))*128 + c4); \
        a0 = fmaf((W), v.x, a0); a1 = fmaf((W), v.y, a1); \
        a2 = fmaf((W), v.z, a2); a3 = fmaf((W), v.w, a3); }
        RC(w00*wz0, xi0, yi0, zi0); RC(w00*lz, xi0, yi0, zi1);
        RC(w01*wz0, xi0, yi1, zi0); RC(w01*lz, xi0, yi1, zi1);
        RC(w10*wz0, xi1, yi0, zi0); RC(w10*lz, xi1, yi0, zi1);
        RC(w11*wz0, xi1, yi1, zi0); RC(w11*lz, xi1, yi1, zi1);
#undef RC
        const int m = n * 49 + xq * 7 + yq;
        ushort4 o;
        o.x = f2bf(a0); o.y = f2bf(a1); o.z = f2bf(a2); o.w = f2bf(a3);
        *(ushort4*)(A1 + (size_t)m * 896 + zq * 128 + c4) = o;
    }
}

// ---------------------------------------------------------------------------
// conv_w [896,128,7] f32 -> WcT [896 r][896 k] bf16, k = z*128+c
// ---------------------------------------------------------------------------
__global__ __launch_bounds__(256) void k_prep_wc(
    const float* __restrict__ w, u16* __restrict__ out)
{
    const int i = blockIdx.x * 256 + threadIdx.x;   // < 802816 exactly
    const int r = i / 896, k = i % 896;
    const int z = k >> 7, c = k & 127;
    out[i] = f2bf(w[(r * 128 + c) * 7 + z]);
}

// ---------------------------------------------------------------------------
// transpose+cast: in f32 [Kin][896] -> out bf16 [896][Kin]
// PERM=1: out[r][kp] = in[(kp%896)*49 + kp/896][r]  (fc6 k-permutation)
// ---------------------------------------------------------------------------
template <int PERM>
__global__ __launch_bounds__(256) void k_transpose(
    const float* __restrict__ in, u16* __restrict__ out, int Kin)
{
    __shared__ u16 tile[64][72];
    const int kp0 = blockIdx.x * 64, r0 = blockIdx.y * 64;
    const int t = threadIdx.x;
#pragma unroll
    for (int it = 0; it < 16; ++it) {
        const int idx = it * 256 + t;
        const int i = idx >> 6, rl = idx & 63;
        const int kp = kp0 + i;
        const int k = PERM ? (kp % 896) * 49 + (kp / 896) : kp;
        tile[i][rl] = f2bf(in[(size_t)k * 896 + r0 + rl]);
    }
    __syncthreads();
#pragma unroll
    for (int it = 0; it < 16; ++it) {
        const int idx = it * 256 + t;
        const int rl = idx >> 6, i = idx & 63;
        out[(size_t)(r0 + rl) * Kin + kp0 + i] = tile[i][rl];
    }
}

// ---------------------------------------------------------------------------
// GEMM: C[M,N] = A[M,K] * Bt[N,K]^T, bf16 inputs, fp32 accum.
// 128x128 tile, BK=32, 4 waves (2x2), per-wave 4x4 of 16x16x32 MFMA.
// Pipeline: depth-2 prefetch, 3 LDS buffers, counted s_waitcnt vmcnt(4)
// (T4: never drain to 0 in main loop). One raw s_barrier per K-step;
// the buffer written at step t is the one read at step t-1 (safe: all
// waves passed barrier(t) after finishing t-1 reads). m201 hazard profile.
// SWZ=1: GEMM1 1-D grid 2744 = 8 XCD x 343 (nt fastest).
// SWZ=2: GEMM2 1-D grid 1344 = 8 XCD x (3 kz-slabs x 56 tiles) — each XCD
//        owns 3 complete split-K slabs -> B-slices fetched once per XCD.
// SWZ=0: 3-D grid (GEMM3).
// EPI==0: out bf16 = acc + bias[n]; fused BN sum/sumsq atomics.
// EPI==1: fp32 partial store to outF + kz * partStride (split-K).
// ---------------------------------------------------------------------------
template <int EPI, int SWZ>
__global__ __launch_bounds__(256) void k_gemm(
    const u16* __restrict__ A, const u16* __restrict__ Bt,
    float* __restrict__ outF, u16* __restrict__ outH,
    const float* __restrict__ bias, float* __restrict__ bnsum, float* __restrict__ bnsq,
    int Astride, int Bstride, int kpc, int ktot, int partStride)
{
    __shared__ __align__(16) u16 lA[3 * 4096];   // 3 buffers x 8 KB
    __shared__ __align__(16) u16 lB[3 * 4096];
    const int t = threadIdx.x;
    const int wave = t >> 6, lane = t & 63;
    const int wm = wave & 1, wn = wave >> 1;
    const int quad = lane >> 4, lr = lane & 15;

    int mt, nt, kz;
    if (SWZ == 1) {
        const int wg = blockIdx.x;                 // 2744 = 8 * 343
        const int swz = (wg & 7) * 343 + (wg >> 3);
        nt = swz % 7; mt = swz / 7; kz = 0;
    } else if (SWZ == 2) {
        const int wg = blockIdx.x;                 // 1344 = 8 * (3 * 56)
        const int xcd = wg & 7, local = wg >> 3;   // local 0..167
        const int kzl = local / 56, rem = local % 56;
        kz = xcd * 3 + kzl;                        // 3 slabs per XCD
        nt = rem >> 3; mt = rem & 7;               // mt fastest: B-slice hot
    } else {
        mt = blockIdx.x; nt = blockIdx.y; kz = blockIdx.z;
    }
    const size_t m0 = (size_t)mt * 128;
    const size_t n0 = (size_t)nt * 128;
    const int kbeg = kz * kpc;
    const int kend = min(kbeg + kpc, ktot);
    const int nstep = kend - kbeg;

    floatx4 acc[4][4];
    const floatx4 zero = {0.f, 0.f, 0.f, 0.f};
#pragma unroll
    for (int a = 0; a < 4; ++a)
#pragma unroll
        for (int bq = 0; bq < 4; ++bq) acc[a][bq] = zero;

    // staging: chunk c in [0,8) = LDS bytes [c*1024, c*1024+1024)
    //        = tile rows c*16 + (lane>>2), elements (lane&3)*8 .. +7
    const int ch0 = wave * 2, ch1 = ch0 + 1;
    const int sr0 = ch0 * 16 + (lane >> 2);
    const int sr1 = sr0 + 16;
    const int sc  = (lane & 3) * 8;
    const u16* gA0 = A  + (m0 + sr0) * (size_t)Astride + (size_t)kbeg * 32 + sc;
    const u16* gA1 = A  + (m0 + sr1) * (size_t)Astride + (size_t)kbeg * 32 + sc;
    const u16* gB0 = Bt + (n0 + sr0) * (size_t)Bstride + (size_t)kbeg * 32 + sc;
    const u16* gB1 = Bt + (n0 + sr1) * (size_t)Bstride + (size_t)kbeg * 32 + sc;
    const int lo0 = ch0 * 512, lo1 = ch1 * 512;  // u16 offsets, wave-uniform

#define STAGE(la_, lb_) { \
    gload16(gA0, (la_) + lo0); gload16(gA1, (la_) + lo1); \
    gload16(gB0, (lb_) + lo0); gload16(gB1, (lb_) + lo1); \
    gA0 += 32; gA1 += 32; gB0 += 32; gB1 += 32; }

    // rotating buffers: read pA0, next-read pA1, write-target pA2
    u16 *pA0 = lA, *pA1 = lA + 4096, *pA2 = lA + 8192;
    u16 *pB0 = lB, *pB1 = lB + 4096, *pB2 = lB + 8192;

    STAGE(pA0, pB0);
    if (nstep > 1) STAGE(pA1, pB1);

    for (int ts = 0; ts < nstep; ++ts) {
        if (ts + 1 < nstep) {
            asm volatile("s_waitcnt vmcnt(4)" ::: "memory");  // tile ts landed
        } else {
            asm volatile("s_waitcnt vmcnt(0)" ::: "memory");  // final tile
        }
        __builtin_amdgcn_sched_barrier(0);
        __builtin_amdgcn_s_barrier();          // all waves' loads landed;
                                               // all waves done reading ts-1
        if (ts + 2 < nstep) STAGE(pA2, pB2);   // 2-ahead into ts-1's buffer
        asm volatile("" ::: "memory");
        bf16x8 af[4], bfr[4];
#pragma unroll
        for (int mt4 = 0; mt4 < 4; ++mt4)
            af[mt4] = *(const bf16x8*)(pA0 + (wm * 64 + mt4 * 16 + lr) * 32 + quad * 8);
#pragma unroll
        for (int nt4 = 0; nt4 < 4; ++nt4)
            bfr[nt4] = *(const bf16x8*)(pB0 + (wn * 64 + nt4 * 16 + lr) * 32 + quad * 8);
#pragma unroll
        for (int mt4 = 0; mt4 < 4; ++mt4)
#pragma unroll
            for (int nt4 = 0; nt4 < 4; ++nt4)
                acc[mt4][nt4] = __builtin_amdgcn_mfma_f32_16x16x32_bf16(
                    af[mt4], bfr[nt4], acc[mt4][nt4], 0, 0, 0);
        u16* tp;
        tp = pA0; pA0 = pA1; pA1 = pA2; pA2 = tp;
        tp = pB0; pB0 = pB1; pB1 = pB2; pB2 = tp;
    }
#undef STAGE

    if (EPI == 0) {
#pragma unroll
        for (int nt4 = 0; nt4 < 4; ++nt4) {
            const int n = (int)n0 + wn * 64 + nt4 * 16 + lr;
            const float bv = bias[n];
            float s1 = 0.f, s2 = 0.f;
#pragma unroll
            for (int mt4 = 0; mt4 < 4; ++mt4) {
#pragma unroll
                for (int j = 0; j < 4; ++j) {
                    const int m = (int)m0 + wm * 64 + mt4 * 16 + quad * 4 + j;
                    const float v = acc[mt4][nt4][j] + bv;
                    outH[(size_t)m * 896 + n] = f2bf(v);
                    s1 += v;
                    s2 = fmaf(v, v, s2);
                }
            }
            s1 += __shfl_xor(s1, 16); s1 += __shfl_xor(s1, 32);
            s2 += __shfl_xor(s2, 16); s2 += __shfl_xor(s2, 32);
            if (quad == 0) {
                atomicAdd(&bnsum[n], s1);
                atomicAdd(&bnsq[n],  s2);
            }
        }
    } else {
        float* po = outF + (size_t)kz * partStride;
#pragma unroll
        for (int nt4 = 0; nt4 < 4; ++nt4) {
            const int n = (int)n0 + wn * 64 + nt4 * 16 + lr;
#pragma unroll
            for (int mt4 = 0; mt4 < 4; ++mt4) {
#pragma unroll
                for (int j = 0; j < 4; ++j) {
                    const int m = (int)m0 + wm * 64 + mt4 * 16 + quad * 4 + j;
                    po[(size_t)m * 896 + n] = acc[mt4][nt4][j];
                }
            }
        }
    }
}

// ---------------------------------------------------------------------------
// BN apply + ReLU, in place on y bf16 [50176, 896] (becomes x2)
// ---------------------------------------------------------------------------
__global__ __launch_bounds__(256) void k_bn_apply(
    u16* __restrict__ y, const float* __restrict__ s1, const float* __restrict__ s2,
    const float* __restrict__ gamma, const float* __restrict__ beta)
{
    const size_t i = ((size_t)blockIdx.x * 256 + threadIdx.x) * 8;
    uint4 d = *(const uint4*)(y + i);
    const u16* h = (const u16*)&d;
    const int r0 = (int)(i % 896);
    __align__(16) u16 o[8];
    const float invM = 1.0f / 50176.0f;
#pragma unroll
    for (int j = 0; j < 8; ++j) {
        const int r = r0 + j;
        const float mu  = s1[r] * invM;
        const float var = fmaf(-mu, mu, s2[r] * invM);
        const float rs  = rsqrtf(var + 1e-5f);
        const float v   = (bf2f(h[j]) - mu) * rs * gamma[r] + beta[r];
        o[j] = f2bf(fmaxf(v, 0.f));
    }
    *(uint4*)(y + i) = *(const uint4*)o;
}

// ---------------------------------------------------------------------------
// split-K reduce + bias + relu -> bf16 (fc6 out / GEMM3 input), 24 chunks
// ---------------------------------------------------------------------------
__global__ __launch_bounds__(256) void k_x3(
    const float* __restrict__ part, const float* __restrict__ bias, u16* __restrict__ x3)
{
    const size_t i = ((size_t)blockIdx.x * 256 + threadIdx.x) * 4;
    float a0=0.f, a1=0.f, a2=0.f, a3=0.f;
#pragma unroll
    for (int c = 0; c < 24; ++c) {
        const float4 v = *(const float4*)(part + (size_t)c * 917504 + i);
        a0 += v.x; a1 += v.y; a2 += v.z; a3 += v.w;
    }
    const int r = (int)(i % 896);
    ushort4 o;
    o.x = f2bf(fmaxf(a0 + bias[r+0], 0.f));
    o.y = f2bf(fmaxf(a1 + bias[r+1], 0.f));
    o.z = f2bf(fmaxf(a2 + bias[r+2], 0.f));
    o.w = f2bf(fmaxf(a3 + bias[r+3], 0.f));
    *(ushort4*)(x3 + i) = o;
}

// split-K reduce + bias + relu -> fp32 final output, 7 chunks
__global__ __launch_bounds__(256) void k_out(
    const float* __restrict__ part, const float* __restrict__ bias, float* __restrict__ out)
{
    const size_t i = ((size_t)blockIdx.x * 256 + threadIdx.x) * 4;
    float a0=0.f, a1=0.f, a2=0.f, a3=0.f;
#pragma unroll
    for (int c = 0; c < 7; ++c) {
        const float4 v = *(const float4*)(part + (size_t)c * 917504 + i);
        a0 += v.x; a1 += v.y; a2 += v.z; a3 += v.w;
    }
    const int r = (int)(i % 896);
    float4 o;
    o.x = fmaxf(a0 + bias[r+0], 0.f);
    o.y = fmaxf(a1 + bias[r+1], 0.f);
    o.z = fmaxf(a2 + bias[r+2], 0.f);
    o.w = fmaxf(a3 + bias[r+3], 0.f);
    *(float4*)(out + i) = o;
}

// ---------------------------------------------------------------------------
extern "C" void kernel_launch(void* const* d_in, const int* in_sizes, int n_in,
                              void* d_out, int out_size, void* d_ws, size_t ws_size,
                              hipStream_t stream)
{
    (void)in_sizes; (void)n_in; (void)out_size; (void)ws_size;
    const float* features = (const float*)d_in[0];
    const float* boxes    = (const float*)d_in[1];
    const float* conv_w   = (const float*)d_in[2];
    const float* conv_b   = (const float*)d_in[3];
    const float* gamma    = (const float*)d_in[4];
    const float* beta     = (const float*)d_in[5];
    const float* fc6_w    = (const float*)d_in[6];
    const float* fc6_b    = (const float*)d_in[7];
    const float* fc7_w    = (const float*)d_in[8];
    const float* fc7_b    = (const float*)d_in[9];
    const int*   batch_idx = (const int*)d_in[10];
    float* out = (float*)d_out;
    char* ws = (char*)d_ws;

    size_t off = 0;
    auto alloc = [&](size_t b) { size_t o = off; off += (b + 255) & ~(size_t)255; return o; };
    const size_t oA1   = alloc(50176ull * 896 * 2);   // 89,915,392
    const size_t oWcT  = alloc(896ull * 896 * 2);
    const size_t oY    = alloc(50176ull * 896 * 2);
    const size_t oF6T  = alloc(43904ull * 896 * 2);   // 78,675,968
    const size_t oF7T  = alloc(896ull * 896 * 2);
    const size_t oStat = alloc(8192);
    // A1 region is dead after GEMM1 -> reuse:
    //   P2: 24 * 917504 * 4 = 88,080,384  (split-K 24 partials, fc6)
    //   X3: at oA1 + 88,080,384 (1,835,008 B -> exactly fills 89,915,392)
    //   P3: overlaps dead P2 (GEMM3 runs after k_x3)
    const size_t oP2 = oA1;
    const size_t oX3 = oA1 + 88080384;
    const size_t oP3 = oA1;

    u16*   A1    = (u16*)(ws + oA1);
    u16*   WcT   = (u16*)(ws + oWcT);
    u16*   Y     = (u16*)(ws + oY);
    u16*   F6T   = (u16*)(ws + oF6T);
    u16*   F7T   = (u16*)(ws + oF7T);
    float* bnsum = (float*)(ws + oStat);
    float* bnsq  = bnsum + 1024;
    float* P2    = (float*)(ws + oP2);
    u16*   X3    = (u16*)(ws + oX3);
    float* P3    = (float*)(ws + oP3);

    // weight prep
    k_prep_wc<<<3136, 256, 0, stream>>>(conv_w, WcT);
    k_transpose<1><<<dim3(686, 14), 256, 0, stream>>>(fc6_w, F6T, 43904);
    k_transpose<0><<<dim3(14, 14), 256, 0, stream>>>(fc7_w, F7T, 896);
    hipMemsetAsync(ws + oStat, 0, 8192, stream);

    // ROIAlign -> A1 [50176, 896] bf16
    k_roialign<<<1024, 256, 0, stream>>>(features, boxes, batch_idx, A1);

    // GEMM1: y = A1 @ WcT^T + conv_b, fused BN stats. M=50176 N=896 K=896
    k_gemm<0, 1><<<dim3(2744, 1, 1), 256, 0, stream>>>(
        A1, WcT, nullptr, Y, conv_b, bnsum, bnsq, 896, 896, 28, 28, 0);

    // BN + ReLU in place (Y becomes x2 viewed as [1024, 43904], k'=xy*896+r)
    k_bn_apply<<<21952, 256, 0, stream>>>(Y, bnsum, bnsq, gamma, beta);

    // GEMM2 (fc6): M=1024 N=896 K=43904, split-K 24 -> P2 (kpc=58, last=38)
    // 1-D grid 1344, XCD-slab swizzled
    k_gemm<1, 2><<<dim3(1344, 1, 1), 256, 0, stream>>>(
        Y, F6T, P2, nullptr, nullptr, nullptr, nullptr, 43904, 43904, 58, 1372, 917504);
    k_x3<<<896, 256, 0, stream>>>(P2, fc6_b, X3);

    // GEMM3 (fc7): M=1024 N=896 K=896, split-K 7 -> P3 (kpc=4, 7*4=28 exact)
    k_gemm<1, 0><<<dim3(8, 7, 7), 256, 0, stream>>>(
        X3, F7T, P3, nullptr, nullptr, nullptr, nullptr, 896, 896, 4, 28, 917504);
    k_out<<<896, 256, 0, stream>>>(P3, fc7_b, out);
}

// Round 4
// 708.085 us; speedup vs baseline: 1.1487x; 1.0613x over previous
//
#include <hip/hip_runtime.h>
#include <cstdint>

typedef unsigned short u16;
using bf16x8  = __attribute__((ext_vector_type(8))) __bf16;
using floatx4 = __attribute__((ext_vector_type(4))) float;

__device__ __forceinline__ u16 f2bf(float f) {
    uint32_t u = __builtin_bit_cast(uint32_t, f);
    u += 0x7fffu + ((u >> 16) & 1u);   // RNE
    return (u16)(u >> 16);
}
__device__ __forceinline__ float bf2f(u16 h) {
    uint32_t u = ((uint32_t)h) << 16;
    return __builtin_bit_cast(float, u);
}

// async global->LDS, 16B per lane (global_load_lds_dwordx4).
// LDS dest is wave-uniform base + lane*16; global src is per-lane.
__device__ __forceinline__ void gload16(const u16* g, u16* l) {
    __builtin_amdgcn_global_load_lds(
        (const __attribute__((address_space(1))) unsigned int*)g,
        (__attribute__((address_space(3))) unsigned int*)l,
        16, 0, 0);
}

// ---------------------------------------------------------------------------
// ROIAlign: feat [2,80,80,20,128] f32 -> A1 [50176, 896] bf16, k = z*128+c
// ---------------------------------------------------------------------------
__global__ __launch_bounds__(256) void k_roialign(
    const float* __restrict__ feat, const float* __restrict__ boxes,
    const int* __restrict__ bidx, u16* __restrict__ A1)
{
    const int n = blockIdx.x;
    const int t = threadIdx.x;
    const float s = 5.0f; // VOXEL_SCALE * POOLER_SCALE
    const float x1 = boxes[n*6+0]*s, y1 = boxes[n*6+1]*s, z1 = boxes[n*6+2]*s;
    const float x2 = boxes[n*6+3]*s, y2 = boxes[n*6+4]*s, z2 = boxes[n*6+5]*s;
    const float binx = fmaxf(x2-x1, 1.0f) * (1.0f/7.0f);
    const float biny = fmaxf(y2-y1, 1.0f) * (1.0f/7.0f);
    const float binz = fmaxf(z2-z1, 1.0f) * (1.0f/7.0f);
    const int b = bidx[n];
    const float* fb = feat + (size_t)b * 80 * 80 * 20 * 128;
    const int c4   = (t & 31) * 4;
    const int slot = t >> 5;

    for (int p = slot; p < 343; p += 8) {
        const int xq = p / 49;
        const int rem = p - xq * 49;
        const int yq = rem / 7;
        const int zq = rem - yq * 7;
        const float px = x1 + ((float)xq + 0.5f) * binx;
        const float py = y1 + ((float)yq + 0.5f) * biny;
        const float pz = z1 + ((float)zq + 0.5f) * binz;
        const float fx = floorf(px), fy = floorf(py), fz = floorf(pz);
        const float lx = px - fx, ly = py - fy, lz = pz - fz;
        const int xi0 = min(max((int)fx,     0), 79);
        const int xi1 = min(max((int)fx + 1, 0), 79);
        const int yi0 = min(max((int)fy,     0), 79);
        const int yi1 = min(max((int)fy + 1, 0), 79);
        const int zi0 = min(max((int)fz,     0), 19);
        const int zi1 = min(max((int)fz + 1, 0), 19);
        const float wx0 = 1.f-lx, wy0 = 1.f-ly, wz0 = 1.f-lz;
        const float w00 = wx0*wy0, w01 = wx0*ly, w10 = lx*wy0, w11 = lx*ly;
        float a0=0.f, a1=0.f, a2=0.f, a3=0.f;
#define RC(W, XI, YI, ZI) { \
        const float4 v = *(const float4*)(fb + (size_t)(((XI)*80+(YI))*20+(ZI))*128 + c4); \
        a0 = fmaf((W), v.x, a0); a1 = fmaf((W), v.y, a1); \
        a2 = fmaf((W), v.z, a2); a3 = fmaf((W), v.w, a3); }
        RC(w00*wz0, xi0, yi0, zi0); RC(w00*lz, xi0, yi0, zi1);
        RC(w01*wz0, xi0, yi1, zi0); RC(w01*lz, xi0, yi1, zi1);
        RC(w10*wz0, xi1, yi0, zi0); RC(w10*lz, xi1, yi0, zi1);
        RC(w11*wz0, xi1, yi1, zi0); RC(w11*lz, xi1, yi1, zi1);
#undef RC
        const int m = n * 49 + xq * 7 + yq;
        ushort4 o;
        o.x = f2bf(a0); o.y = f2bf(a1); o.z = f2bf(a2); o.w = f2bf(a3);
        *(ushort4*)(A1 + (size_t)m * 896 + zq * 128 + c4) = o;
    }
}

// ---------------------------------------------------------------------------
// conv_w [896,128,7] f32 -> WcT [896 r][896 k] bf16, k = z*128+c
// ---------------------------------------------------------------------------
__global__ __launch_bounds__(256) void k_prep_wc(
    const float* __restrict__ w, u16* __restrict__ out)
{
    const int i = blockIdx.x * 256 + threadIdx.x;   // < 802816 exactly
    const int r = i / 896, k = i % 896;
    const int z = k >> 7, c = k & 127;
    out[i] = f2bf(w[(r * 128 + c) * 7 + z]);
}

// ---------------------------------------------------------------------------
// transpose+cast: in f32 [Kin][896] -> out bf16 [896][Kin]
// PERM=1: out[r][kp] = in[(kp%896)*49 + kp/896][r]  (fc6 k-permutation)
// ---------------------------------------------------------------------------
template <int PERM>
__global__ __launch_bounds__(256) void k_transpose(
    const float* __restrict__ in, u16* __restrict__ out, int Kin)
{
    __shared__ u16 tile[64][72];
    const int kp0 = blockIdx.x * 64, r0 = blockIdx.y * 64;
    const int t = threadIdx.x;
#pragma unroll
    for (int it = 0; it < 16; ++it) {
        const int idx = it * 256 + t;
        const int i = idx >> 6, rl = idx & 63;
        const int kp = kp0 + i;
        const int k = PERM ? (kp % 896) * 49 + (kp / 896) : kp;
        tile[i][rl] = f2bf(in[(size_t)k * 896 + r0 + rl]);
    }
    __syncthreads();
#pragma unroll
    for (int it = 0; it < 16; ++it) {
        const int idx = it * 256 + t;
        const int rl = idx >> 6, i = idx & 63;
        out[(size_t)(r0 + rl) * Kin + kp0 + i] = tile[i][rl];
    }
}

// ---------------------------------------------------------------------------
// GEMM: C[M,N] = A[M,K] * Bt[N,K]^T, bf16 inputs, fp32 accum.
// 256x128 tile, BK=32, 8 waves (4M x 2N), per-wave 4x4 of 16x16x32 MFMA.
// Pipeline (verbatim from verified round-3 kernel): depth-2 prefetch,
// 3 LDS buffers, counted s_waitcnt vmcnt(3) (3 gloads/wave/stage), one
// raw s_barrier per K-step; write target = buffer read at step ts-1.
// 2x MFMA per step vs 128^2 amortizes the fixed per-step serial cost
// (barrier + ds_read latency) that capped MfmaUtil at 24%.
// SWZ=1: GEMM1, nwg=1372, bijective m204 XCD swizzle (q=171,r=4), nt fastest.
// SWZ=2: GEMM2, nwg=504=8*63; g=(wg&7)*63+wg/8; kz=g/28, mt fastest.
// SWZ=0: 3-D grid (GEMM3).
// EPI==0: out bf16 = acc + bias[n]; fused BN sum/sumsq atomics.
// EPI==1: fp32 partial store to outF + kz * partStride (split-K).
// ---------------------------------------------------------------------------
template <int EPI, int SWZ>
__global__ __launch_bounds__(512) void k_gemm(
    const u16* __restrict__ A, const u16* __restrict__ Bt,
    float* __restrict__ outF, u16* __restrict__ outH,
    const float* __restrict__ bias, float* __restrict__ bnsum, float* __restrict__ bnsq,
    int Astride, int Bstride, int kpc, int ktot, int partStride)
{
    __shared__ __align__(16) u16 lA[3 * 8192];   // 3 buffers x 16 KB (256x32)
    __shared__ __align__(16) u16 lB[3 * 4096];   // 3 buffers x  8 KB (128x32)
    const int t = threadIdx.x;
    const int wave = t >> 6, lane = t & 63;
    const int wm = wave >> 1, wn = wave & 1;     // 4M x 2N wave grid
    const int quad = lane >> 4, lr = lane & 15;

    int mt, nt, kz;
    if (SWZ == 1) {
        const int wg = blockIdx.x;               // 1372 = 8*171 + 4
        const int xcd = wg & 7, i = wg >> 3;
        const int q = 171, r = 4;
        const int base = (xcd < r) ? xcd * (q + 1) : r * (q + 1) + (xcd - r) * q;
        const int swz = base + i;
        nt = swz % 7; mt = swz / 7; kz = 0;      // nt fastest: A-panel hot in XCD L2
    } else if (SWZ == 2) {
        const int wg = blockIdx.x;               // 504 = 8 * 63
        const int g = (wg & 7) * 63 + (wg >> 3);
        kz = g / 28;
        const int rem = g % 28;
        nt = rem >> 2; mt = rem & 3;             // mt fastest: B-slice hot
    } else {
        mt = blockIdx.x; nt = blockIdx.y; kz = blockIdx.z;
    }
    const size_t m0 = (size_t)mt * 256;
    const size_t n0 = (size_t)nt * 128;
    const int kbeg = kz * kpc;
    const int kend = min(kbeg + kpc, ktot);
    const int nstep = kend - kbeg;

    floatx4 acc[4][4];
    const floatx4 zero = {0.f, 0.f, 0.f, 0.f};
#pragma unroll
    for (int a = 0; a < 4; ++a)
#pragma unroll
        for (int bq = 0; bq < 4; ++bq) acc[a][bq] = zero;

    // staging: A = 16 chunks of 1 KB (16 rows x 64 B); wave w owns chunks 2w,2w+1.
    //          B = 8 chunks; wave w owns chunk w. lane l: row ch*16 + l/4,
    //          bytes (l&3)*16 within the 64 B row -> linear LDS [rows][32] u16.
    const int chA0 = wave * 2, chA1 = chA0 + 1, chB = wave;
    const int srA0 = chA0 * 16 + (lane >> 2);
    const int srA1 = srA0 + 16;
    const int srB  = chB * 16 + (lane >> 2);
    const int sc   = (lane & 3) * 8;
    const u16* gA0 = A  + (m0 + srA0) * (size_t)Astride + (size_t)kbeg * 32 + sc;
    const u16* gA1 = A  + (m0 + srA1) * (size_t)Astride + (size_t)kbeg * 32 + sc;
    const u16* gB0 = Bt + (n0 + srB ) * (size_t)Bstride + (size_t)kbeg * 32 + sc;
    const int loA0 = chA0 * 512, loA1 = chA1 * 512, loB = chB * 512;  // u16 offs

#define STAGE(la_, lb_) { \
    gload16(gA0, (la_) + loA0); gload16(gA1, (la_) + loA1); \
    gload16(gB0, (lb_) + loB); \
    gA0 += 32; gA1 += 32; gB0 += 32; }

    // rotating buffers: read pA0, next-read pA1, write-target pA2
    u16 *pA0 = lA, *pA1 = lA + 8192, *pA2 = lA + 16384;
    u16 *pB0 = lB, *pB1 = lB + 4096, *pB2 = lB + 8192;

    STAGE(pA0, pB0);
    if (nstep > 1) STAGE(pA1, pB1);

    for (int ts = 0; ts < nstep; ++ts) {
        if (ts + 1 < nstep) {
            asm volatile("s_waitcnt vmcnt(3)" ::: "memory");  // tile ts landed
        } else {
            asm volatile("s_waitcnt vmcnt(0)" ::: "memory");  // final tile
        }
        __builtin_amdgcn_sched_barrier(0);
        __builtin_amdgcn_s_barrier();          // all waves' loads landed;
                                               // all waves done reading ts-1
        if (ts + 2 < nstep) STAGE(pA2, pB2);   // 2-ahead into ts-1's buffer
        asm volatile("" ::: "memory");
        bf16x8 af[4], bfr[4];
#pragma unroll
        for (int mt4 = 0; mt4 < 4; ++mt4)
            af[mt4] = *(const bf16x8*)(pA0 + (wm * 64 + mt4 * 16 + lr) * 32 + quad * 8);
#pragma unroll
        for (int nt4 = 0; nt4 < 4; ++nt4)
            bfr[nt4] = *(const bf16x8*)(pB0 + (wn * 64 + nt4 * 16 + lr) * 32 + quad * 8);
#pragma unroll
        for (int mt4 = 0; mt4 < 4; ++mt4)
#pragma unroll
            for (int nt4 = 0; nt4 < 4; ++nt4)
                acc[mt4][nt4] = __builtin_amdgcn_mfma_f32_16x16x32_bf16(
                    af[mt4], bfr[nt4], acc[mt4][nt4], 0, 0, 0);
        u16* tp;
        tp = pA0; pA0 = pA1; pA1 = pA2; pA2 = tp;
        tp = pB0; pB0 = pB1; pB1 = pB2; pB2 = tp;
    }
#undef STAGE

    if (EPI == 0) {
#pragma unroll
        for (int nt4 = 0; nt4 < 4; ++nt4) {
            const int n = (int)n0 + wn * 64 + nt4 * 16 + lr;
            const float bv = bias[n];
            float s1 = 0.f, s2 = 0.f;
#pragma unroll
            for (int mt4 = 0; mt4 < 4; ++mt4) {
#pragma unroll
                for (int j = 0; j < 4; ++j) {
                    const int m = (int)m0 + wm * 64 + mt4 * 16 + quad * 4 + j;
                    const float v = acc[mt4][nt4][j] + bv;
                    outH[(size_t)m * 896 + n] = f2bf(v);
                    s1 += v;
                    s2 = fmaf(v, v, s2);
                }
            }
            s1 += __shfl_xor(s1, 16); s1 += __shfl_xor(s1, 32);
            s2 += __shfl_xor(s2, 16); s2 += __shfl_xor(s2, 32);
            if (quad == 0) {
                atomicAdd(&bnsum[n], s1);
                atomicAdd(&bnsq[n],  s2);
            }
        }
    } else {
        float* po = outF + (size_t)kz * partStride;
#pragma unroll
        for (int nt4 = 0; nt4 < 4; ++nt4) {
            const int n = (int)n0 + wn * 64 + nt4 * 16 + lr;
#pragma unroll
            for (int mt4 = 0; mt4 < 4; ++mt4) {
#pragma unroll
                for (int j = 0; j < 4; ++j) {
                    const int m = (int)m0 + wm * 64 + mt4 * 16 + quad * 4 + j;
                    po[(size_t)m * 896 + n] = acc[mt4][nt4][j];
                }
            }
        }
    }
}

// ---------------------------------------------------------------------------
// BN apply + ReLU, in place on y bf16 [50176, 896] (becomes x2)
// ---------------------------------------------------------------------------
__global__ __launch_bounds__(256) void k_bn_apply(
    u16* __restrict__ y, const float* __restrict__ s1, const float* __restrict__ s2,
    const float* __restrict__ gamma, const float* __restrict__ beta)
{
    const size_t i = ((size_t)blockIdx.x * 256 + threadIdx.x) * 8;
    uint4 d = *(const uint4*)(y + i);
    const u16* h = (const u16*)&d;
    const int r0 = (int)(i % 896);
    __align__(16) u16 o[8];
    const float invM = 1.0f / 50176.0f;
#pragma unroll
    for (int j = 0; j < 8; ++j) {
        const int r = r0 + j;
        const float mu  = s1[r] * invM;
        const float var = fmaf(-mu, mu, s2[r] * invM);
        const float rs  = rsqrtf(var + 1e-5f);
        const float v   = (bf2f(h[j]) - mu) * rs * gamma[r] + beta[r];
        o[j] = f2bf(fmaxf(v, 0.f));
    }
    *(uint4*)(y + i) = *(const uint4*)o;
}

// ---------------------------------------------------------------------------
// split-K reduce + bias + relu -> bf16 (fc6 out / GEMM3 input), 18 chunks
// ---------------------------------------------------------------------------
__global__ __launch_bounds__(256) void k_x3(
    const float* __restrict__ part, const float* __restrict__ bias, u16* __restrict__ x3)
{
    const size_t i = ((size_t)blockIdx.x * 256 + threadIdx.x) * 4;
    float a0=0.f, a1=0.f, a2=0.f, a3=0.f;
#pragma unroll
    for (int c = 0; c < 18; ++c) {
        const float4 v = *(const float4*)(part + (size_t)c * 917504 + i);
        a0 += v.x; a1 += v.y; a2 += v.z; a3 += v.w;
    }
    const int r = (int)(i % 896);
    ushort4 o;
    o.x = f2bf(fmaxf(a0 + bias[r+0], 0.f));
    o.y = f2bf(fmaxf(a1 + bias[r+1], 0.f));
    o.z = f2bf(fmaxf(a2 + bias[r+2], 0.f));
    o.w = f2bf(fmaxf(a3 + bias[r+3], 0.f));
    *(ushort4*)(x3 + i) = o;
}

// split-K reduce + bias + relu -> fp32 final output, 7 chunks
__global__ __launch_bounds__(256) void k_out(
    const float* __restrict__ part, const float* __restrict__ bias, float* __restrict__ out)
{
    const size_t i = ((size_t)blockIdx.x * 256 + threadIdx.x) * 4;
    float a0=0.f, a1=0.f, a2=0.f, a3=0.f;
#pragma unroll
    for (int c = 0; c < 7; ++c) {
        const float4 v = *(const float4*)(part + (size_t)c * 917504 + i);
        a0 += v.x; a1 += v.y; a2 += v.z; a3 += v.w;
    }
    const int r = (int)(i % 896);
    float4 o;
    o.x = fmaxf(a0 + bias[r+0], 0.f);
    o.y = fmaxf(a1 + bias[r+1], 0.f);
    o.z = fmaxf(a2 + bias[r+2], 0.f);
    o.w = fmaxf(a3 + bias[r+3], 0.f);
    *(float4*)(out + i) = o;
}

// ---------------------------------------------------------------------------
extern "C" void kernel_launch(void* const* d_in, const int* in_sizes, int n_in,
                              void* d_out, int out_size, void* d_ws, size_t ws_size,
                              hipStream_t stream)
{
    (void)in_sizes; (void)n_in; (void)out_size; (void)ws_size;
    const float* features = (const float*)d_in[0];
    const float* boxes    = (const float*)d_in[1];
    const float* conv_w   = (const float*)d_in[2];
    const float* conv_b   = (const float*)d_in[3];
    const float* gamma    = (const float*)d_in[4];
    const float* beta     = (const float*)d_in[5];
    const float* fc6_w    = (const float*)d_in[6];
    const float* fc6_b    = (const float*)d_in[7];
    const float* fc7_w    = (const float*)d_in[8];
    const float* fc7_b    = (const float*)d_in[9];
    const int*   batch_idx = (const int*)d_in[10];
    float* out = (float*)d_out;
    char* ws = (char*)d_ws;

    size_t off = 0;
    auto alloc = [&](size_t b) { size_t o = off; off += (b + 255) & ~(size_t)255; return o; };
    const size_t oA1   = alloc(50176ull * 896 * 2);   // 89,915,392
    const size_t oWcT  = alloc(896ull * 896 * 2);
    const size_t oY    = alloc(50176ull * 896 * 2);
    const size_t oF6T  = alloc(43904ull * 896 * 2);   // 78,675,968
    const size_t oF7T  = alloc(896ull * 896 * 2);
    const size_t oStat = alloc(8192);
    // A1 region is dead after GEMM1 -> reuse:
    //   P2: 18 * 917504 * 4 = 66,060,288  (split-K 18 partials, fc6)
    //   X3: at oA1 + 66,060,288 (1,835,008 B -> 67.9 MB < 89.9 MB)
    //   P3: overlaps dead P2 (GEMM3 runs after k_x3): 7 * 3,670,016 = 25.7 MB
    const size_t oP2 = oA1;
    const size_t oX3 = oA1 + 66060288;
    const size_t oP3 = oA1;

    u16*   A1    = (u16*)(ws + oA1);
    u16*   WcT   = (u16*)(ws + oWcT);
    u16*   Y     = (u16*)(ws + oY);
    u16*   F6T   = (u16*)(ws + oF6T);
    u16*   F7T   = (u16*)(ws + oF7T);
    float* bnsum = (float*)(ws + oStat);
    float* bnsq  = bnsum + 1024;
    float* P2    = (float*)(ws + oP2);
    u16*   X3    = (u16*)(ws + oX3);
    float* P3    = (float*)(ws + oP3);

    // weight prep
    k_prep_wc<<<3136, 256, 0, stream>>>(conv_w, WcT);
    k_transpose<1><<<dim3(686, 14), 256, 0, stream>>>(fc6_w, F6T, 43904);
    k_transpose<0><<<dim3(14, 14), 256, 0, stream>>>(fc7_w, F7T, 896);
    hipMemsetAsync(ws + oStat, 0, 8192, stream);

    // ROIAlign -> A1 [50176, 896] bf16
    k_roialign<<<1024, 256, 0, stream>>>(features, boxes, batch_idx, A1);

    // GEMM1: y = A1 @ WcT^T + conv_b, fused BN stats. M=50176 N=896 K=896
    // 256x128 tile: 196 mt x 7 nt = 1372 blocks, bijective XCD swizzle
    k_gemm<0, 1><<<dim3(1372, 1, 1), 512, 0, stream>>>(
        A1, WcT, nullptr, Y, conv_b, bnsum, bnsq, 896, 896, 28, 28, 0);

    // BN + ReLU in place (Y becomes x2 viewed as [1024, 43904], k'=xy*896+r)
    k_bn_apply<<<21952, 256, 0, stream>>>(Y, bnsum, bnsq, gamma, beta);

    // GEMM2 (fc6): M=1024 N=896 K=43904, split-K 18 -> P2 (kpc=77, last=63)
    // 504 = 8*63 blocks: fully resident in one scheduling round, no tail
    k_gemm<1, 2><<<dim3(504, 1, 1), 512, 0, stream>>>(
        Y, F6T, P2, nullptr, nullptr, nullptr, nullptr, 43904, 43904, 77, 1372, 917504);
    k_x3<<<896, 256, 0, stream>>>(P2, fc6_b, X3);

    // GEMM3 (fc7): M=1024 N=896 K=896, split-K 7 -> P3 (kpc=4, 7*4=28 exact)
    k_gemm<1, 0><<<dim3(4, 7, 7), 512, 0, stream>>>(
        X3, F7T, P3, nullptr, nullptr, nullptr, nullptr, 896, 896, 4, 28, 917504);
    k_out<<<896, 256, 0, stream>>>(P3, fc7_b, out);
}